// Round 1
// baseline (3121.688 us; speedup 1.0000x reference)
//
#include <hip/hip_runtime.h>
#include <cstdint>
#include <cstddef>

#define D_FEAT 128
#define D 64
#define SLOPE 0.01f

__device__ __forceinline__ float leaky(float v) { return v >= 0.f ? v : SLOPE * v; }

// x = L2-normalize-rows(F @ Wm + bm);  F: [N,128], Wm: [128,64]
__global__ __launch_bounds__(256) void k_mlp_norm(const float* __restrict__ F,
    const float* __restrict__ Wm, const float* __restrict__ bm,
    float* __restrict__ X, int N)
{
    __shared__ float Ws[D_FEAT * D];
    __shared__ float xs[4][D_FEAT];
    for (int i = threadIdx.x; i < D_FEAT * D; i += 256) Ws[i] = Wm[i];
    __syncthreads();
    int lane = threadIdx.x & 63, wav = threadIdx.x >> 6;
    int node = blockIdx.x * 4 + wav;
    if (node >= N) return;
    const float* fr = F + (size_t)node * D_FEAT;
    xs[wav][lane]      = fr[lane];
    xs[wav][lane + 64] = fr[lane + 64];
    float acc = bm[lane];
#pragma unroll
    for (int k = 0; k < D_FEAT; ++k)
        acc = fmaf(xs[wav][k], Ws[k * D + lane], acc);
    float sq = acc * acc;
#pragma unroll
    for (int off = 32; off; off >>= 1) sq += __shfl_xor(sq, off);
    float inv = 1.f / fmaxf(sqrtf(sq), 1e-12f);
    X[(size_t)node * D + lane] = acc * inv;
}

// Y = X @ W  (64x64), no bias/activation
__global__ __launch_bounds__(256) void k_mm64(const float* __restrict__ X,
    const float* __restrict__ W, float* __restrict__ Y, int N)
{
    __shared__ float Ws[D * D];
    __shared__ float xs[4][D];
    for (int i = threadIdx.x; i < D * D; i += 256) Ws[i] = W[i];
    __syncthreads();
    int lane = threadIdx.x & 63, wav = threadIdx.x >> 6;
    int node = blockIdx.x * 4 + wav;
    if (node >= N) return;
    xs[wav][lane] = X[(size_t)node * D + lane];
    float acc = 0.f;
#pragma unroll
    for (int k = 0; k < D; ++k)
        acc = fmaf(xs[wav][k], Ws[k * D + lane], acc);
    Y[(size_t)node * D + lane] = acc;
}

// H[dst] += Y[src] over edges; 4 edges per wave, float4 per lane
__global__ __launch_bounds__(256) void k_scatter(const int* __restrict__ esrc,
    const int* __restrict__ edst, const float* __restrict__ Y,
    float* __restrict__ H, int E)
{
    int gw = (blockIdx.x * 256 + threadIdx.x) >> 6;
    int lane = threadIdx.x & 63;
    int sub = lane >> 4, q = lane & 15;
    int nw = (gridDim.x * 256) >> 6;
    for (int e0 = gw * 4; e0 < E; e0 += nw * 4) {
        int e = e0 + sub;
        if (e < E) {
            int s = esrc[e], d = edst[e];
            float4 v = *((const float4*)(Y + (size_t)s * D) + q);
            float* hp = H + (size_t)d * D + (q << 2);
            atomicAdd(hp + 0, v.x);
            atomicAdd(hp + 1, v.y);
            atomicAdd(hp + 2, v.z);
            atomicAdd(hp + 3, v.w);
        }
    }
}

// O = leaky( leaky(H)@Wg + bg + leaky(X@Wl + bl) + ID )   (row-wise, in-place safe)
__global__ __launch_bounds__(256) void k_combine(const float* __restrict__ X,
    const float* __restrict__ H, const float* __restrict__ Wl, const float* __restrict__ bl,
    const float* __restrict__ Wg, const float* __restrict__ bg,
    const float* __restrict__ ID, float* __restrict__ O, int N)
{
    __shared__ float Wls[D * D], Wgs[D * D];
    __shared__ float xs[4][D], hs[4][D];
    for (int i = threadIdx.x; i < D * D; i += 256) { Wls[i] = Wl[i]; Wgs[i] = Wg[i]; }
    __syncthreads();
    int lane = threadIdx.x & 63, wav = threadIdx.x >> 6;
    int node = blockIdx.x * 4 + wav;
    if (node >= N) return;
    xs[wav][lane] = X[(size_t)node * D + lane];
    hs[wav][lane] = leaky(H[(size_t)node * D + lane]);
    float al = bl[lane], ag = bg[lane];
#pragma unroll
    for (int k = 0; k < D; ++k) {
        al = fmaf(xs[wav][k], Wls[k * D + lane], al);
        ag = fmaf(hs[wav][k], Wgs[k * D + lane], ag);
    }
    float xhat = leaky(al) + ID[(size_t)node * D + lane];
    O[(size_t)node * D + lane] = leaky(ag + xhat);
}

extern "C" void kernel_launch(void* const* d_in, const int* in_sizes, int n_in,
                              void* d_out, int out_size, void* d_ws, size_t ws_size,
                              hipStream_t stream)
{
    const float* features = (const float*)d_in[0];
    const float* id_emb   = (const float*)d_in[1];
    const int*   eidx     = (const int*)d_in[2];
    const float* W_mlp    = (const float*)d_in[3];
    const float* b_mlp    = (const float*)d_in[4];
    const float* Wc1 = (const float*)d_in[5];
    const float* Wl1 = (const float*)d_in[6];
    const float* bl1 = (const float*)d_in[7];
    const float* Wg1 = (const float*)d_in[8];
    const float* bg1 = (const float*)d_in[9];
    const float* Wc2 = (const float*)d_in[10];
    const float* Wl2 = (const float*)d_in[11];
    const float* bl2 = (const float*)d_in[12];
    const float* Wg2 = (const float*)d_in[13];
    const float* bg2 = (const float*)d_in[14];

    int N = in_sizes[0] / D_FEAT;
    int E = in_sizes[2] / 2;
    const int* esrc = eidx;
    const int* edst = eidx + E;

    float* x = (float*)d_ws;           // [N,64]
    float* y = x + (size_t)N * D;      // [N,64]
    float* h = (float*)d_out;          // [N,64] — reuse output buffer as conv accumulator

    int nb = (N + 3) / 4;
    dim3 blk(256);

    k_mlp_norm<<<nb, blk, 0, stream>>>(features, W_mlp, b_mlp, x, N);

    // layer 1
    k_mm64<<<nb, blk, 0, stream>>>(x, Wc1, y, N);
    hipMemsetAsync(h, 0, (size_t)N * D * sizeof(float), stream);
    k_scatter<<<2048, blk, 0, stream>>>(esrc, edst, y, h, E);
    k_combine<<<nb, blk, 0, stream>>>(x, h, Wl1, bl1, Wg1, bg1, id_emb, x, N);

    // layer 2
    k_mm64<<<nb, blk, 0, stream>>>(x, Wc2, y, N);
    hipMemsetAsync(h, 0, (size_t)N * D * sizeof(float), stream);
    k_scatter<<<2048, blk, 0, stream>>>(esrc, edst, y, h, E);
    k_combine<<<nb, blk, 0, stream>>>(x, h, Wl2, bl2, Wg2, bg2, id_emb, (float*)d_out, N);
}

// Round 2
// 989.949 us; speedup vs baseline: 3.1534x; 3.1534x over previous
//
#include <hip/hip_runtime.h>
#include <cstdint>
#include <cstddef>

#define D_FEAT 128
#define D 64
#define SLOPE 0.01f

__device__ __forceinline__ float leaky(float v) { return v >= 0.f ? v : SLOPE * v; }

// x = L2-normalize-rows(F @ Wm + bm);  F: [N,128], Wm: [128,64]
__global__ __launch_bounds__(256) void k_mlp_norm(const float* __restrict__ F,
    const float* __restrict__ Wm, const float* __restrict__ bm,
    float* __restrict__ X, int N)
{
    __shared__ float Ws[D_FEAT * D];
    __shared__ float xs[4][D_FEAT];
    for (int i = threadIdx.x; i < D_FEAT * D; i += 256) Ws[i] = Wm[i];
    __syncthreads();
    int lane = threadIdx.x & 63, wav = threadIdx.x >> 6;
    int node = blockIdx.x * 4 + wav;
    if (node >= N) return;
    const float* fr = F + (size_t)node * D_FEAT;
    xs[wav][lane]      = fr[lane];
    xs[wav][lane + 64] = fr[lane + 64];
    float acc = bm[lane];
#pragma unroll
    for (int k = 0; k < D_FEAT; ++k)
        acc = fmaf(xs[wav][k], Ws[k * D + lane], acc);
    float sq = acc * acc;
#pragma unroll
    for (int off = 32; off; off >>= 1) sq += __shfl_xor(sq, off);
    float inv = 1.f / fmaxf(sqrtf(sq), 1e-12f);
    X[(size_t)node * D + lane] = acc * inv;
}

// histogram: off[dst]++ over edges
__global__ __launch_bounds__(256) void k_hist(const int* __restrict__ edst,
    int* __restrict__ off, int E)
{
    int e = blockIdx.x * 256 + threadIdx.x;
    if (e < E) atomicAdd(&off[edst[e]], 1);
}

// single-block exclusive scan over off[0..N) in place
__global__ __launch_bounds__(1024) void k_scan(int* __restrict__ off, int N)
{
    __shared__ int tsum[1024];
    int tid = threadIdx.x;
    int chunk = (N + 1023) / 1024;
    int lo = tid * chunk, hi = lo + chunk;
    if (hi > N) hi = N;
    int s = 0;
    for (int i = lo; i < hi; ++i) s += off[i];
    tsum[tid] = s;
    __syncthreads();
    // Hillis-Steele inclusive scan over tsum
    for (int d = 1; d < 1024; d <<= 1) {
        int v = tsum[tid];
        int add = (tid >= d) ? tsum[tid - d] : 0;
        __syncthreads();
        tsum[tid] = v + add;
        __syncthreads();
    }
    int base = (tid > 0) ? tsum[tid - 1] : 0;   // exclusive base for this chunk
    for (int i = lo; i < hi; ++i) {
        int v = off[i];
        off[i] = base;
        base += v;
    }
}

// placement: srcs_sorted[atomicAdd(&off[dst],1)] = src
// afterwards off[i] == end offset of node i (start = off[i-1], or 0)
__global__ __launch_bounds__(256) void k_place(const int* __restrict__ esrc,
    const int* __restrict__ edst, int* __restrict__ off,
    int* __restrict__ srcs, int E)
{
    int e = blockIdx.x * 256 + threadIdx.x;
    if (e < E) {
        int d = edst[e];
        int idx = atomicAdd(&off[d], 1);
        srcs[idx] = esrc[e];
    }
}

// agg[n] = sum over edges (dst==n) of X[src]; one wave per node
__global__ __launch_bounds__(256) void k_gather(const int* __restrict__ off,
    const int* __restrict__ srcs, const float* __restrict__ X,
    float* __restrict__ A, int N)
{
    int lane = threadIdx.x & 63, wav = threadIdx.x >> 6;
    int node = blockIdx.x * 4 + wav;
    if (node >= N) return;
    int start = (node > 0) ? off[node - 1] : 0;
    int end = off[node];
    float acc = 0.f;
    for (int base = start; base < end; base += 64) {
        int m = end - base; if (m > 64) m = 64;
        int sid = (lane < m) ? srcs[base + lane] : 0;
        for (int j = 0; j < m; ++j) {
            int s = __shfl(sid, j);
            acc += X[(size_t)s * D + lane];
        }
    }
    A[(size_t)node * D + lane] = acc;
}

// O = leaky( leaky(A@Wc)@Wg + bg + leaky(X@Wl + bl) + ID )  (row-wise, in-place safe)
__global__ __launch_bounds__(256) void k_combine(const float* __restrict__ X,
    const float* __restrict__ A,
    const float* __restrict__ Wc,
    const float* __restrict__ Wl, const float* __restrict__ bl,
    const float* __restrict__ Wg, const float* __restrict__ bg,
    const float* __restrict__ ID, float* __restrict__ O, int N)
{
    __shared__ float Wcs[D * D], Wls[D * D], Wgs[D * D];
    __shared__ float xs[4][D], as_[4][D], ts[4][D];
    for (int i = threadIdx.x; i < D * D; i += 256) {
        Wcs[i] = Wc[i]; Wls[i] = Wl[i]; Wgs[i] = Wg[i];
    }
    __syncthreads();
    int lane = threadIdx.x & 63, wav = threadIdx.x >> 6;
    int node = blockIdx.x * 4 + wav;
    if (node >= N) return;
    xs[wav][lane]  = X[(size_t)node * D + lane];
    as_[wav][lane] = A[(size_t)node * D + lane];
    float ac = 0.f, al = bl[lane];
#pragma unroll
    for (int k = 0; k < D; ++k) {
        ac = fmaf(as_[wav][k], Wcs[k * D + lane], ac);
        al = fmaf(xs[wav][k],  Wls[k * D + lane], al);
    }
    ts[wav][lane] = leaky(ac);          // h = leaky(conv)
    float ag = bg[lane];
#pragma unroll
    for (int k = 0; k < D; ++k)
        ag = fmaf(ts[wav][k], Wgs[k * D + lane], ag);
    float xhat = leaky(al) + ID[(size_t)node * D + lane];
    O[(size_t)node * D + lane] = leaky(ag + xhat);
}

extern "C" void kernel_launch(void* const* d_in, const int* in_sizes, int n_in,
                              void* d_out, int out_size, void* d_ws, size_t ws_size,
                              hipStream_t stream)
{
    const float* features = (const float*)d_in[0];
    const float* id_emb   = (const float*)d_in[1];
    const int*   eidx     = (const int*)d_in[2];
    const float* W_mlp    = (const float*)d_in[3];
    const float* b_mlp    = (const float*)d_in[4];
    const float* Wc1 = (const float*)d_in[5];
    const float* Wl1 = (const float*)d_in[6];
    const float* bl1 = (const float*)d_in[7];
    const float* Wg1 = (const float*)d_in[8];
    const float* bg1 = (const float*)d_in[9];
    const float* Wc2 = (const float*)d_in[10];
    const float* Wl2 = (const float*)d_in[11];
    const float* bl2 = (const float*)d_in[12];
    const float* Wg2 = (const float*)d_in[13];
    const float* bg2 = (const float*)d_in[14];

    int N = in_sizes[0] / D_FEAT;
    int E = in_sizes[2] / 2;
    const int* esrc = eidx;
    const int* edst = eidx + E;

    float* x   = (float*)d_ws;                   // [N,64] fp32
    int*  offs = (int*)(x + (size_t)N * D);      // [N]
    int*  srcs = offs + N;                       // [E]
    float* agg = (float*)d_out;                  // [N,64] — reuse output buffer

    int nb = (N + 3) / 4;
    dim3 blk(256);

    // CSR build (edge_index is shared by both layers)
    hipMemsetAsync(offs, 0, (size_t)N * sizeof(int), stream);
    k_hist <<<(E + 255) / 256, blk, 0, stream>>>(edst, offs, E);
    k_scan <<<1, 1024, 0, stream>>>(offs, N);
    k_place<<<(E + 255) / 256, blk, 0, stream>>>(esrc, edst, offs, srcs, E);

    k_mlp_norm<<<nb, blk, 0, stream>>>(features, W_mlp, b_mlp, x, N);

    // layer 1
    k_gather <<<nb, blk, 0, stream>>>(offs, srcs, x, agg, N);
    k_combine<<<nb, blk, 0, stream>>>(x, agg, Wc1, Wl1, bl1, Wg1, bg1, id_emb, x, N);

    // layer 2
    k_gather <<<nb, blk, 0, stream>>>(offs, srcs, x, agg, N);
    k_combine<<<nb, blk, 0, stream>>>(x, agg, Wc2, Wl2, bl2, Wg2, bg2, id_emb,
                                      (float*)d_out, N);
}

// Round 3
// 545.146 us; speedup vs baseline: 5.7263x; 1.8159x over previous
//
#include <hip/hip_runtime.h>
#include <cstdint>
#include <cstddef>

#define D 64
#define D_FEAT 128
#define SLOPE 0.01f

typedef __attribute__((ext_vector_type(8))) short bf16x8;
typedef __attribute__((ext_vector_type(4))) float f32x4;

__device__ __forceinline__ float leaky(float v) { return v >= 0.f ? v : SLOPE * v; }

__device__ __forceinline__ unsigned short f2bf(float f) {
    union { float f; unsigned u; } v; v.f = f;
    unsigned r = v.u + 0x7FFF + ((v.u >> 16) & 1);   // RNE
    return (unsigned short)(r >> 16);
}
__device__ __forceinline__ float bf2f(unsigned short b) {
    union { unsigned u; float f; } v; v.u = ((unsigned)b) << 16;
    return v.f;
}

// B-fragment of row-major fp32 W[K][64] for 16x16x32 MFMA:
// lane holds col = nt*16+(lane&15), k = ks*32+(lane>>4)*8+j
__device__ __forceinline__ bf16x8 wfrag(const float* W, int ks, int nt, int lane) {
    int col = nt * 16 + (lane & 15);
    int k0 = ks * 32 + ((lane >> 4) << 3);
    bf16x8 r;
#pragma unroll
    for (int j = 0; j < 8; ++j)
        r[j] = (short)f2bf(W[(k0 + j) * 64 + col]);
    return r;
}

// ---------------- CSR build ----------------
__global__ __launch_bounds__(256) void k_hist(const int* __restrict__ edst,
    int* __restrict__ off, int E)
{
    int e = blockIdx.x * 256 + threadIdx.x;
    if (e < E) atomicAdd(&off[edst[e]], 1);
}

__global__ __launch_bounds__(1024) void k_scan(int* __restrict__ off, int N)
{
    __shared__ int tsum[1024];
    int tid = threadIdx.x;
    int chunk = (N + 1023) / 1024;
    int lo = tid * chunk, hi = lo + chunk;
    if (hi > N) hi = N;
    int s = 0;
    for (int i = lo; i < hi; ++i) s += off[i];
    tsum[tid] = s;
    __syncthreads();
    for (int d = 1; d < 1024; d <<= 1) {
        int v = tsum[tid];
        int add = (tid >= d) ? tsum[tid - d] : 0;
        __syncthreads();
        tsum[tid] = v + add;
        __syncthreads();
    }
    int base = (tid > 0) ? tsum[tid - 1] : 0;
    for (int i = lo; i < hi; ++i) {
        int v = off[i];
        off[i] = base;
        base += v;
    }
}

__global__ __launch_bounds__(256) void k_place(const int* __restrict__ esrc,
    const int* __restrict__ edst, int* __restrict__ off,
    int* __restrict__ srcs, int E)
{
    int e = blockIdx.x * 256 + threadIdx.x;
    if (e < E) {
        int d = edst[e];
        int idx = atomicAdd(&off[d], 1);
        srcs[idx] = esrc[e];
    }
}

// ---------------- MLP + L2 norm (MFMA), fp32 in -> bf16 out ----------------
__global__ __launch_bounds__(256) void k_mlp(const float* __restrict__ F,
    const float* __restrict__ Wm, const float* __restrict__ bm,
    unsigned short* __restrict__ Xb, int N)
{
    int lane = threadIdx.x & 63, w = threadIdx.x >> 6;
    int cl = lane & 15, g = lane >> 4;
    int ntiles = (N + 63) / 64;

    bf16x8 Wmf[4][4];
#pragma unroll
    for (int ks = 0; ks < 4; ++ks)
#pragma unroll
        for (int nt = 0; nt < 4; ++nt)
            Wmf[ks][nt] = wfrag(Wm, ks, nt, lane);
    float bmv[4];
#pragma unroll
    for (int nt = 0; nt < 4; ++nt) bmv[nt] = bm[nt * 16 + cl];

    for (int tb = blockIdx.x; tb < ntiles; tb += gridDim.x) {
        int node0 = tb * 64 + w * 16;
        if (node0 >= N) continue;
        f32x4 acc[4];
#pragma unroll
        for (int nt = 0; nt < 4; ++nt) acc[nt] = (f32x4){0.f, 0.f, 0.f, 0.f};
#pragma unroll
        for (int ks = 0; ks < 4; ++ks) {
            const float4* fp = (const float4*)(F + (size_t)(node0 + cl) * D_FEAT + ks * 32 + g * 8);
            float4 a = fp[0], b = fp[1];
            bf16x8 af;
            af[0] = (short)f2bf(a.x); af[1] = (short)f2bf(a.y);
            af[2] = (short)f2bf(a.z); af[3] = (short)f2bf(a.w);
            af[4] = (short)f2bf(b.x); af[5] = (short)f2bf(b.y);
            af[6] = (short)f2bf(b.z); af[7] = (short)f2bf(b.w);
#pragma unroll
            for (int nt = 0; nt < 4; ++nt)
                acc[nt] = __builtin_amdgcn_mfma_f32_16x16x32_bf16(af, Wmf[ks][nt], acc[nt], 0, 0, 0);
        }
        float ss[4] = {0.f, 0.f, 0.f, 0.f};
#pragma unroll
        for (int nt = 0; nt < 4; ++nt)
#pragma unroll
            for (int i = 0; i < 4; ++i) {
                float v = acc[nt][i] + bmv[nt];
                acc[nt][i] = v;
                ss[i] += v * v;
            }
#pragma unroll
        for (int off = 8; off >= 1; off >>= 1)
#pragma unroll
            for (int i = 0; i < 4; ++i)
                ss[i] += __shfl_xor(ss[i], off);
        float inv[4];
#pragma unroll
        for (int i = 0; i < 4; ++i)
            inv[i] = 1.f / fmaxf(sqrtf(ss[i]), 1e-12f);
#pragma unroll
        for (int nt = 0; nt < 4; ++nt)
#pragma unroll
            for (int i = 0; i < 4; ++i)
                Xb[(size_t)(node0 + g * 4 + i) * D + nt * 16 + cl] = f2bf(acc[nt][i] * inv[i]);
    }
}

// ---------------- gather: Agg[n] = sum_{edges dst==n} Xb[src] ----------------
__global__ __launch_bounds__(256) void k_gather(const int* __restrict__ off,
    const int* __restrict__ srcs, const unsigned short* __restrict__ Xb,
    unsigned short* __restrict__ Ab, int N)
{
    int lane = threadIdx.x & 63, w = threadIdx.x >> 6;
    int node = blockIdx.x * 4 + w;
    if (node >= N) return;
    int start = node ? off[node - 1] : 0;
    int end = off[node];
    int half = lane >> 5;
    int c2 = (lane & 31) * 2;
    float2 acc = {0.f, 0.f};
    for (int base = start; base < end; base += 64) {
        int m = end - base; if (m > 64) m = 64;
        int sid = (base + lane < end) ? srcs[base + lane] : 0;
        int iters = (m + 1) >> 1;
        for (int j = 0; j < iters; ++j) {
            int idx = (j << 1) | half;
            int s = __shfl(sid, idx);
            if (idx < m) {
                unsigned u = *(const unsigned*)(Xb + (size_t)s * D + c2);
                acc.x += bf2f((unsigned short)(u & 0xFFFFu));
                acc.y += bf2f((unsigned short)(u >> 16));
            }
        }
    }
    acc.x += __shfl_xor(acc.x, 32);
    acc.y += __shfl_xor(acc.y, 32);
    if (half == 0) {
        unsigned o = (unsigned)f2bf(acc.x) | ((unsigned)f2bf(acc.y) << 16);
        *(unsigned*)(Ab + (size_t)node * D + c2) = o;
    }
}

// ---------------- fused combine (MFMA):
// O = leaky( leaky(Agg@Wc)@Wg + bg + leaky(X@Wl + bl) + ID ) ----------------
__global__ __launch_bounds__(256) void k_combine(
    const unsigned short* Xb, const unsigned short* __restrict__ Ab,
    const float* __restrict__ Wc,
    const float* __restrict__ Wl, const float* __restrict__ bl,
    const float* __restrict__ Wg, const float* __restrict__ bg,
    const float* __restrict__ ID,
    unsigned short* Ob, float* Of, int N)
{
    __shared__ unsigned short tl[4][16][72];   // per-wave transpose buffer (+pad)
    int lane = threadIdx.x & 63, w = threadIdx.x >> 6;
    int cl = lane & 15, g = lane >> 4;
    int ntiles = (N + 63) / 64;

    bf16x8 Wcf[2][4], Wlf[2][4], Wgf[2][4];
#pragma unroll
    for (int ks = 0; ks < 2; ++ks)
#pragma unroll
        for (int nt = 0; nt < 4; ++nt) {
            Wcf[ks][nt] = wfrag(Wc, ks, nt, lane);
            Wlf[ks][nt] = wfrag(Wl, ks, nt, lane);
            Wgf[ks][nt] = wfrag(Wg, ks, nt, lane);
        }
    float blv[4], bgv[4];
#pragma unroll
    for (int nt = 0; nt < 4; ++nt) {
        blv[nt] = bl[nt * 16 + cl];
        bgv[nt] = bg[nt * 16 + cl];
    }

    for (int tb = blockIdx.x; tb < ntiles; tb += gridDim.x) {
        int node0 = tb * 64 + w * 16;
        bool active = node0 < N;
        f32x4 accL[4], accG[4];
        if (active) {
            const bf16x8* xr = (const bf16x8*)(Xb + (size_t)(node0 + cl) * D + g * 8);
            const bf16x8* ar = (const bf16x8*)(Ab + (size_t)(node0 + cl) * D + g * 8);
            bf16x8 xf0 = xr[0], xf1 = xr[4];
            bf16x8 af0 = ar[0], af1 = ar[4];
            f32x4 accC[4];
#pragma unroll
            for (int nt = 0; nt < 4; ++nt) {
                f32x4 z = (f32x4){0.f, 0.f, 0.f, 0.f};
                accL[nt] = __builtin_amdgcn_mfma_f32_16x16x32_bf16(xf1, Wlf[1][nt],
                            __builtin_amdgcn_mfma_f32_16x16x32_bf16(xf0, Wlf[0][nt], z, 0, 0, 0), 0, 0, 0);
                accC[nt] = __builtin_amdgcn_mfma_f32_16x16x32_bf16(af1, Wcf[1][nt],
                            __builtin_amdgcn_mfma_f32_16x16x32_bf16(af0, Wcf[0][nt], z, 0, 0, 0), 0, 0, 0);
            }
            // t = leaky(conv) -> LDS in C-layout (row=g*4+i, col=nt*16+cl)
#pragma unroll
            for (int nt = 0; nt < 4; ++nt)
#pragma unroll
                for (int i = 0; i < 4; ++i)
                    tl[w][g * 4 + i][nt * 16 + cl] = f2bf(leaky(accC[nt][i]));
        }
        __syncthreads();
        if (active) {
            const bf16x8* tr = (const bf16x8*)&tl[w][cl][g * 8];
            bf16x8 tf0 = tr[0], tf1 = tr[4];
#pragma unroll
            for (int nt = 0; nt < 4; ++nt) {
                f32x4 z = (f32x4){0.f, 0.f, 0.f, 0.f};
                accG[nt] = __builtin_amdgcn_mfma_f32_16x16x32_bf16(tf1, Wgf[1][nt],
                            __builtin_amdgcn_mfma_f32_16x16x32_bf16(tf0, Wgf[0][nt], z, 0, 0, 0), 0, 0, 0);
            }
#pragma unroll
            for (int nt = 0; nt < 4; ++nt) {
                int col = nt * 16 + cl;
#pragma unroll
                for (int i = 0; i < 4; ++i) {
                    size_t row = (size_t)(node0 + g * 4 + i);
                    float xh = leaky(accL[nt][i] + blv[nt]) + ID[row * D + col];
                    float o = leaky(accG[nt][i] + bgv[nt] + xh);
                    if (Ob) Ob[row * D + col] = f2bf(o);
                    else    Of[row * D + col] = o;
                }
            }
        }
        __syncthreads();
    }
}

extern "C" void kernel_launch(void* const* d_in, const int* in_sizes, int n_in,
                              void* d_out, int out_size, void* d_ws, size_t ws_size,
                              hipStream_t stream)
{
    const float* features = (const float*)d_in[0];
    const float* id_emb   = (const float*)d_in[1];
    const int*   eidx     = (const int*)d_in[2];
    const float* W_mlp    = (const float*)d_in[3];
    const float* b_mlp    = (const float*)d_in[4];
    const float* Wc1 = (const float*)d_in[5];
    const float* Wl1 = (const float*)d_in[6];
    const float* bl1 = (const float*)d_in[7];
    const float* Wg1 = (const float*)d_in[8];
    const float* bg1 = (const float*)d_in[9];
    const float* Wc2 = (const float*)d_in[10];
    const float* Wl2 = (const float*)d_in[11];
    const float* bl2 = (const float*)d_in[12];
    const float* Wg2 = (const float*)d_in[13];
    const float* bg2 = (const float*)d_in[14];

    int N = in_sizes[0] / D_FEAT;
    int E = in_sizes[2] / 2;
    const int* esrc = eidx;
    const int* edst = eidx + E;

    unsigned short* Xb = (unsigned short*)d_ws;          // [N][64] bf16
    unsigned short* Ab = Xb + (size_t)N * D;             // [N][64] bf16
    int* offs = (int*)(Ab + (size_t)N * D);              // [N]
    int* srcs = offs + N;                                // [E]

    dim3 blk(256);
    int ntiles = (N + 63) / 64;
    int cgrid = ntiles < 512 ? ntiles : 512;

    // CSR build (shared by both layers)
    hipMemsetAsync(offs, 0, (size_t)N * sizeof(int), stream);
    k_hist <<<(E + 255) / 256, blk, 0, stream>>>(edst, offs, E);
    k_scan <<<1, 1024, 0, stream>>>(offs, N);
    k_place<<<(E + 255) / 256, blk, 0, stream>>>(esrc, edst, offs, srcs, E);

    k_mlp<<<cgrid, blk, 0, stream>>>(features, W_mlp, b_mlp, Xb, N);

    // layer 1  (combine writes x1 bf16 in-place over Xb)
    k_gather <<<(N + 3) / 4, blk, 0, stream>>>(offs, srcs, Xb, Ab, N);
    k_combine<<<cgrid, blk, 0, stream>>>(Xb, Ab, Wc1, Wl1, bl1, Wg1, bg1, id_emb,
                                         Xb, (float*)nullptr, N);

    // layer 2
    k_gather <<<(N + 3) / 4, blk, 0, stream>>>(offs, srcs, Xb, Ab, N);
    k_combine<<<cgrid, blk, 0, stream>>>(Xb, Ab, Wc2, Wl2, bl2, Wg2, bg2, id_emb,
                                         (unsigned short*)nullptr, (float*)d_out, N);
}

// Round 4
// 371.782 us; speedup vs baseline: 8.3966x; 1.4663x over previous
//
#include <hip/hip_runtime.h>
#include <cstdint>
#include <cstddef>

#define D 64
#define D_FEAT 128
#define SLOPE 0.01f

typedef __attribute__((ext_vector_type(8))) short bf16x8;
typedef __attribute__((ext_vector_type(4))) float f32x4;

__device__ __forceinline__ float leaky(float v) { return v >= 0.f ? v : SLOPE * v; }

__device__ __forceinline__ unsigned short f2bf(float f) {
    union { float f; unsigned u; } v; v.f = f;
    unsigned r = v.u + 0x7FFF + ((v.u >> 16) & 1);   // RNE
    return (unsigned short)(r >> 16);
}
__device__ __forceinline__ float bf2f(unsigned short b) {
    union { unsigned u; float f; } v; v.u = ((unsigned)b) << 16;
    return v.f;
}

// B-fragment of row-major fp32 W[K][64] for 16x16x32 MFMA:
// lane holds col = nt*16+(lane&15), k = ks*32+(lane>>4)*8+j
__device__ __forceinline__ bf16x8 wfrag(const float* W, int ks, int nt, int lane) {
    int col = nt * 16 + (lane & 15);
    int k0 = ks * 32 + ((lane >> 4) << 3);
    bf16x8 r;
#pragma unroll
    for (int j = 0; j < 8; ++j)
        r[j] = (short)f2bf(W[(k0 + j) * 64 + col]);
    return r;
}

// ---------------- CSR build ----------------
__global__ __launch_bounds__(256) void k_hist(const int* __restrict__ edst,
    int* __restrict__ off, int E)
{
    int e = blockIdx.x * 256 + threadIdx.x;
    if (e < E) atomicAdd(&off[edst[e]], 1);
}

// phase A: bsum[b] = sum of cnt[b*1024 .. b*1024+1024)
__global__ __launch_bounds__(256) void k_bsum(const int* __restrict__ cnt,
    int* __restrict__ bsum, int N)
{
    __shared__ int wsum[4];
    int idx = blockIdx.x * 1024 + threadIdx.x * 4;
    int s = 0;
    if (idx + 3 < N) {
        int4 v = *(const int4*)(cnt + idx);
        s = v.x + v.y + v.z + v.w;
    } else {
#pragma unroll
        for (int i = 0; i < 4; ++i) if (idx + i < N) s += cnt[idx + i];
    }
#pragma unroll
    for (int d = 32; d; d >>= 1) s += __shfl_xor(s, d);
    int lane = threadIdx.x & 63, w = threadIdx.x >> 6;
    if (!lane) wsum[w] = s;
    __syncthreads();
    if (!threadIdx.x) bsum[blockIdx.x] = wsum[0] + wsum[1] + wsum[2] + wsum[3];
}

// phase B: single-block scan (used on the ~98 block sums) — exclusive, in place
__global__ __launch_bounds__(1024) void k_scan(int* __restrict__ off, int N)
{
    __shared__ int tsum[1024];
    int tid = threadIdx.x;
    int chunk = (N + 1023) / 1024;
    int lo = tid * chunk, hi = lo + chunk;
    if (hi > N) hi = N;
    int s = 0;
    for (int i = lo; i < hi; ++i) s += off[i];
    tsum[tid] = s;
    __syncthreads();
    for (int d = 1; d < 1024; d <<= 1) {
        int v = tsum[tid];
        int add = (tid >= d) ? tsum[tid - d] : 0;
        __syncthreads();
        tsum[tid] = v + add;
        __syncthreads();
    }
    int base = (tid > 0) ? tsum[tid - 1] : 0;
    for (int i = lo; i < hi; ++i) {
        int v = off[i];
        off[i] = base;
        base += v;
    }
}

// phase C: in-place exclusive scan of each 1024-chunk + scanned block base
__global__ __launch_bounds__(256) void k_scan_blk(int* __restrict__ off,
    const int* __restrict__ bbase, int N)
{
    __shared__ int wsum[4];
    int idx = blockIdx.x * 1024 + threadIdx.x * 4;
    int4 v = {0, 0, 0, 0};
    bool full = (idx + 3 < N);
    if (full) v = *(const int4*)(off + idx);
    else {
        if (idx + 0 < N) v.x = off[idx + 0];
        if (idx + 1 < N) v.y = off[idx + 1];
        if (idx + 2 < N) v.z = off[idx + 2];
        if (idx + 3 < N) v.w = off[idx + 3];
    }
    int ts = v.x + v.y + v.z + v.w;
    int lane = threadIdx.x & 63, w = threadIdx.x >> 6;
    int inc = ts;
#pragma unroll
    for (int d = 1; d < 64; d <<= 1) {
        int u = __shfl_up(inc, d);
        if (lane >= d) inc += u;
    }
    if (lane == 63) wsum[w] = inc;
    __syncthreads();
    int wbase = 0;
    for (int i = 0; i < w; ++i) wbase += wsum[i];
    int ex = bbase[blockIdx.x] + wbase + inc - ts;
    int4 o;
    o.x = ex; o.y = ex + v.x; o.z = o.y + v.y; o.w = o.z + v.z;
    if (full) *(int4*)(off + idx) = o;
    else {
        if (idx + 0 < N) off[idx + 0] = o.x;
        if (idx + 1 < N) off[idx + 1] = o.y;
        if (idx + 2 < N) off[idx + 2] = o.z;
        if (idx + 3 < N) off[idx + 3] = o.w;
    }
}

__global__ __launch_bounds__(256) void k_place(const int* __restrict__ esrc,
    const int* __restrict__ edst, int* __restrict__ off,
    int* __restrict__ srcs, int E)
{
    int e = blockIdx.x * 256 + threadIdx.x;
    if (e < E) {
        int d = edst[e];
        int idx = atomicAdd(&off[d], 1);
        srcs[idx] = esrc[e];
    }
}

// ---------------- MLP + L2 norm (MFMA), fp32 in -> bf16 out ----------------
__global__ __launch_bounds__(256) void k_mlp(const float* __restrict__ F,
    const float* __restrict__ Wm, const float* __restrict__ bm,
    unsigned short* __restrict__ Xb, int N)
{
    int lane = threadIdx.x & 63, w = threadIdx.x >> 6;
    int cl = lane & 15, g = lane >> 4;
    int ntiles = (N + 63) / 64;

    bf16x8 Wmf[4][4];
#pragma unroll
    for (int ks = 0; ks < 4; ++ks)
#pragma unroll
        for (int nt = 0; nt < 4; ++nt)
            Wmf[ks][nt] = wfrag(Wm, ks, nt, lane);
    float bmv[4];
#pragma unroll
    for (int nt = 0; nt < 4; ++nt) bmv[nt] = bm[nt * 16 + cl];

    for (int tb = blockIdx.x; tb < ntiles; tb += gridDim.x) {
        int node0 = tb * 64 + w * 16;
        if (node0 >= N) continue;
        f32x4 acc[4];
#pragma unroll
        for (int nt = 0; nt < 4; ++nt) acc[nt] = (f32x4){0.f, 0.f, 0.f, 0.f};
#pragma unroll
        for (int ks = 0; ks < 4; ++ks) {
            const float4* fp = (const float4*)(F + (size_t)(node0 + cl) * D_FEAT + ks * 32 + g * 8);
            float4 a = fp[0], b = fp[1];
            bf16x8 af;
            af[0] = (short)f2bf(a.x); af[1] = (short)f2bf(a.y);
            af[2] = (short)f2bf(a.z); af[3] = (short)f2bf(a.w);
            af[4] = (short)f2bf(b.x); af[5] = (short)f2bf(b.y);
            af[6] = (short)f2bf(b.z); af[7] = (short)f2bf(b.w);
#pragma unroll
            for (int nt = 0; nt < 4; ++nt)
                acc[nt] = __builtin_amdgcn_mfma_f32_16x16x32_bf16(af, Wmf[ks][nt], acc[nt], 0, 0, 0);
        }
        float ss[4] = {0.f, 0.f, 0.f, 0.f};
#pragma unroll
        for (int nt = 0; nt < 4; ++nt)
#pragma unroll
            for (int i = 0; i < 4; ++i) {
                float v = acc[nt][i] + bmv[nt];
                acc[nt][i] = v;
                ss[i] += v * v;
            }
#pragma unroll
        for (int off = 8; off >= 1; off >>= 1)
#pragma unroll
            for (int i = 0; i < 4; ++i)
                ss[i] += __shfl_xor(ss[i], off);
        float inv[4];
#pragma unroll
        for (int i = 0; i < 4; ++i)
            inv[i] = 1.f / fmaxf(sqrtf(ss[i]), 1e-12f);
#pragma unroll
        for (int nt = 0; nt < 4; ++nt)
#pragma unroll
            for (int i = 0; i < 4; ++i)
                Xb[(size_t)(node0 + g * 4 + i) * D + nt * 16 + cl] = f2bf(acc[nt][i] * inv[i]);
    }
}

// ---------------- gather: Agg[n] = sum_{edges dst==n} Xb[src] ----------------
// quarter-wave per edge: 16 lanes x 8B cover one 64xbf16 row; 4 edges/iter
__global__ __launch_bounds__(256) void k_gather(const int* __restrict__ off,
    const int* __restrict__ srcs, const unsigned short* __restrict__ Xb,
    unsigned short* __restrict__ Ab, int N)
{
    int lane = threadIdx.x & 63, w = threadIdx.x >> 6;
    int node = blockIdx.x * 4 + w;
    if (node >= N) return;
    int start = node ? off[node - 1] : 0;
    int end = off[node];
    int q = lane >> 4;
    int c4 = (lane & 15) * 4;
    float4 acc = {0.f, 0.f, 0.f, 0.f};
    for (int base = start; base < end; base += 64) {
        int m = end - base; if (m > 64) m = 64;
        int sid = (base + lane < end) ? srcs[base + lane] : 0;
        int iters = (m + 3) >> 2;
        for (int j = 0; j < iters; ++j) {
            int idx = (j << 2) | q;
            int s = __shfl(sid, idx);
            if (idx < m) {
                uint2 u = *(const uint2*)(Xb + (size_t)s * D + c4);
                acc.x += bf2f((unsigned short)(u.x & 0xFFFFu));
                acc.y += bf2f((unsigned short)(u.x >> 16));
                acc.z += bf2f((unsigned short)(u.y & 0xFFFFu));
                acc.w += bf2f((unsigned short)(u.y >> 16));
            }
        }
    }
#pragma unroll
    for (int d = 32; d >= 16; d >>= 1) {
        acc.x += __shfl_xor(acc.x, d);
        acc.y += __shfl_xor(acc.y, d);
        acc.z += __shfl_xor(acc.z, d);
        acc.w += __shfl_xor(acc.w, d);
    }
    if (q == 0) {
        uint2 o;
        o.x = (unsigned)f2bf(acc.x) | ((unsigned)f2bf(acc.y) << 16);
        o.y = (unsigned)f2bf(acc.z) | ((unsigned)f2bf(acc.w) << 16);
        *(uint2*)(Ab + (size_t)node * D + c4) = o;
    }
}

// ---------------- fused combine (MFMA):
// O = leaky( leaky(Agg@Wc)@Wg + bg + leaky(X@Wl + bl) + ID ) ----------------
__global__ __launch_bounds__(256) void k_combine(
    const unsigned short* Xb, const unsigned short* __restrict__ Ab,
    const float* __restrict__ Wc,
    const float* __restrict__ Wl, const float* __restrict__ bl,
    const float* __restrict__ Wg, const float* __restrict__ bg,
    const float* __restrict__ ID,
    unsigned short* Ob, float* Of, int N)
{
    __shared__ unsigned short tl[4][16][72];   // per-wave transpose buffer (+pad)
    int lane = threadIdx.x & 63, w = threadIdx.x >> 6;
    int cl = lane & 15, g = lane >> 4;
    int ntiles = (N + 63) / 64;

    bf16x8 Wcf[2][4], Wlf[2][4], Wgf[2][4];
#pragma unroll
    for (int ks = 0; ks < 2; ++ks)
#pragma unroll
        for (int nt = 0; nt < 4; ++nt) {
            Wcf[ks][nt] = wfrag(Wc, ks, nt, lane);
            Wlf[ks][nt] = wfrag(Wl, ks, nt, lane);
            Wgf[ks][nt] = wfrag(Wg, ks, nt, lane);
        }
    float blv[4], bgv[4];
#pragma unroll
    for (int nt = 0; nt < 4; ++nt) {
        blv[nt] = bl[nt * 16 + cl];
        bgv[nt] = bg[nt * 16 + cl];
    }

    for (int tb = blockIdx.x; tb < ntiles; tb += gridDim.x) {
        int node0 = tb * 64 + w * 16;
        bool active = node0 < N;
        f32x4 accL[4], accG[4];
        if (active) {
            const bf16x8* xr = (const bf16x8*)(Xb + (size_t)(node0 + cl) * D + g * 8);
            const bf16x8* ar = (const bf16x8*)(Ab + (size_t)(node0 + cl) * D + g * 8);
            bf16x8 xf0 = xr[0], xf1 = xr[4];
            bf16x8 af0 = ar[0], af1 = ar[4];
            f32x4 accC[4];
#pragma unroll
            for (int nt = 0; nt < 4; ++nt) {
                f32x4 z = (f32x4){0.f, 0.f, 0.f, 0.f};
                accL[nt] = __builtin_amdgcn_mfma_f32_16x16x32_bf16(xf1, Wlf[1][nt],
                            __builtin_amdgcn_mfma_f32_16x16x32_bf16(xf0, Wlf[0][nt], z, 0, 0, 0), 0, 0, 0);
                accC[nt] = __builtin_amdgcn_mfma_f32_16x16x32_bf16(af1, Wcf[1][nt],
                            __builtin_amdgcn_mfma_f32_16x16x32_bf16(af0, Wcf[0][nt], z, 0, 0, 0), 0, 0, 0);
            }
#pragma unroll
            for (int nt = 0; nt < 4; ++nt)
#pragma unroll
                for (int i = 0; i < 4; ++i)
                    tl[w][g * 4 + i][nt * 16 + cl] = f2bf(leaky(accC[nt][i]));
        }
        __syncthreads();
        if (active) {
            const bf16x8* tr = (const bf16x8*)&tl[w][cl][g * 8];
            bf16x8 tf0 = tr[0], tf1 = tr[4];
#pragma unroll
            for (int nt = 0; nt < 4; ++nt) {
                f32x4 z = (f32x4){0.f, 0.f, 0.f, 0.f};
                accG[nt] = __builtin_amdgcn_mfma_f32_16x16x32_bf16(tf1, Wgf[1][nt],
                            __builtin_amdgcn_mfma_f32_16x16x32_bf16(tf0, Wgf[0][nt], z, 0, 0, 0), 0, 0, 0);
            }
#pragma unroll
            for (int nt = 0; nt < 4; ++nt) {
                int col = nt * 16 + cl;
#pragma unroll
                for (int i = 0; i < 4; ++i) {
                    size_t row = (size_t)(node0 + g * 4 + i);
                    float xh = leaky(accL[nt][i] + blv[nt]) + ID[row * D + col];
                    float o = leaky(accG[nt][i] + bgv[nt] + xh);
                    if (Ob) Ob[row * D + col] = f2bf(o);
                    else    Of[row * D + col] = o;
                }
            }
        }
        __syncthreads();
    }
}

extern "C" void kernel_launch(void* const* d_in, const int* in_sizes, int n_in,
                              void* d_out, int out_size, void* d_ws, size_t ws_size,
                              hipStream_t stream)
{
    const float* features = (const float*)d_in[0];
    const float* id_emb   = (const float*)d_in[1];
    const int*   eidx     = (const int*)d_in[2];
    const float* W_mlp    = (const float*)d_in[3];
    const float* b_mlp    = (const float*)d_in[4];
    const float* Wc1 = (const float*)d_in[5];
    const float* Wl1 = (const float*)d_in[6];
    const float* bl1 = (const float*)d_in[7];
    const float* Wg1 = (const float*)d_in[8];
    const float* bg1 = (const float*)d_in[9];
    const float* Wc2 = (const float*)d_in[10];
    const float* Wl2 = (const float*)d_in[11];
    const float* bl2 = (const float*)d_in[12];
    const float* Wg2 = (const float*)d_in[13];
    const float* bg2 = (const float*)d_in[14];

    int N = in_sizes[0] / D_FEAT;
    int E = in_sizes[2] / 2;
    const int* esrc = eidx;
    const int* edst = eidx + E;

    unsigned short* Xb = (unsigned short*)d_ws;          // [N][64] bf16
    unsigned short* Ab = Xb + (size_t)N * D;             // [N][64] bf16
    int* offs = (int*)(Ab + (size_t)N * D);              // [N]
    int* srcs = offs + N;                                // [E]
    int* bsum = srcs + E;                                // [ceil(N/1024)]

    dim3 blk(256);
    int ntiles = (N + 63) / 64;
    int cgrid = ntiles < 512 ? ntiles : 512;
    int nb = (N + 1023) / 1024;

    // CSR build (shared by both layers)
    hipMemsetAsync(offs, 0, (size_t)N * sizeof(int), stream);
    k_hist <<<(E + 255) / 256, blk, 0, stream>>>(edst, offs, E);
    k_bsum <<<nb, blk, 0, stream>>>(offs, bsum, N);
    k_scan <<<1, 1024, 0, stream>>>(bsum, nb);
    k_scan_blk<<<nb, blk, 0, stream>>>(offs, bsum, N);
    k_place<<<(E + 255) / 256, blk, 0, stream>>>(esrc, edst, offs, srcs, E);

    k_mlp<<<cgrid, blk, 0, stream>>>(features, W_mlp, b_mlp, Xb, N);

    // layer 1  (combine writes x1 bf16 in-place over Xb)
    k_gather <<<(N + 3) / 4, blk, 0, stream>>>(offs, srcs, Xb, Ab, N);
    k_combine<<<cgrid, blk, 0, stream>>>(Xb, Ab, Wc1, Wl1, bl1, Wg1, bg1, id_emb,
                                         Xb, (float*)nullptr, N);

    // layer 2
    k_gather <<<(N + 3) / 4, blk, 0, stream>>>(offs, srcs, Xb, Ab, N);
    k_combine<<<cgrid, blk, 0, stream>>>(Xb, Ab, Wc2, Wl2, bl2, Wg2, bg2, id_emb,
                                         (unsigned short*)nullptr, (float*)d_out, N);
}